// Round 1
// baseline (209.056 us; speedup 1.0000x reference)
//
#include <hip/hip_runtime.h>

typedef _Float16 f16;
typedef f16 f16x8 __attribute__((ext_vector_type(8)));
typedef f16 f16x4 __attribute__((ext_vector_type(4)));
typedef float f32x4 __attribute__((ext_vector_type(4)));

#define GLL(g, l) __builtin_amdgcn_global_load_lds((const __attribute__((address_space(1))) void*)(g), (__attribute__((address_space(3))) void*)(l), 16, 0, 0)

// ---------------- fp32 -> fp16 convert (x, Wq, Wk, Wv, Wo) ----------------
__global__ __launch_bounds__(256) void cvt_all(
    const float* __restrict__ x, const float* __restrict__ wq, const float* __restrict__ wk,
    const float* __restrict__ wv, const float* __restrict__ wo,
    f16* __restrict__ xh, f16* __restrict__ wqh, f16* __restrict__ wkh,
    f16* __restrict__ wvh, f16* __restrict__ woh)
{
  int i = blockIdx.x * 256 + threadIdx.x;   // vec4 index, total 1835008
  const float4* src; f16x4* dst; int off;
  if (i < 1048576)      { src = (const float4*)x;  dst = (f16x4*)xh;  off = i; }
  else if (i < 1310720) { src = (const float4*)wq; dst = (f16x4*)wqh; off = i - 1048576; }
  else if (i < 1441792) { src = (const float4*)wk; dst = (f16x4*)wkh; off = i - 1310720; }
  else if (i < 1572864) { src = (const float4*)wv; dst = (f16x4*)wvh; off = i - 1441792; }
  else                  { src = (const float4*)wo; dst = (f16x4*)woh; off = i - 1572864; }
  float4 v = src[off];
  f16x4 hv; hv[0] = (f16)v.x; hv[1] = (f16)v.y; hv[2] = (f16)v.z; hv[3] = (f16)v.w;
  dst[off] = hv;
}

// ---------------- GEMM: C = A(MxK) * B(NxK)^T, K=1024, tile 128x128, BK=32 ----------------
// MODE 0: QKV projection. N = 2048 (Q 0..1023, K 1024..1535, V 1536..2047).
//         Writes Q head-major f16, K head-major f16, V TRANSPOSED ([n][kvh][64][2048]) f16.
// MODE 1: out projection. N = 1024. Writes f32 + bias to Co.
template<int MODE>
__global__ __launch_bounds__(256) void gemm_k(
    const f16* __restrict__ A, const f16* __restrict__ B0, const f16* __restrict__ B1,
    const f16* __restrict__ B2,
    f16* __restrict__ Qb, f16* __restrict__ Kb, f16* __restrict__ VTb,
    const float* __restrict__ bo, float* __restrict__ Co)
{
  __shared__ __align__(16) f16 Ah[2][4096];
  __shared__ __align__(16) f16 Bh[2][4096];
  const int tid = threadIdx.x;
  const int bm = blockIdx.x & 31, bn = blockIdx.x >> 5;
  const f16* Bp;
  if (MODE == 0) {
    if (bn < 8)       Bp = B0 + (size_t)bn * 131072;
    else if (bn < 12) Bp = B1 + (size_t)(bn - 8) * 131072;
    else              Bp = B2 + (size_t)(bn - 12) * 131072;
  } else {
    Bp = B0 + (size_t)bn * 131072;
  }
  const f16* Ap = A + (size_t)bm * 131072;

  const int w = tid >> 6, lane = tid & 63, lr = lane & 15, lg = lane >> 4;
  const int wr = w >> 1, wc = w & 1;

  auto stage = [&](int b, int kt) {
#pragma unroll
    for (int i = 0; i < 2; ++i) {
      int o = tid * 16 + i * 4096;          // byte offset within the 8KB tile
      int row = o >> 6, colb = o & 63;
      GLL((const char*)Ap + (size_t)row * 2048 + kt * 64 + colb, (char*)&Ah[b][0] + o);
      GLL((const char*)Bp + (size_t)row * 2048 + kt * 64 + colb, (char*)&Bh[b][0] + o);
    }
  };

  f32x4 acc[4][4] = {};

  stage(0, 0);
  for (int kt = 0; kt < 32; ++kt) {
    const int cur = kt & 1;
    __syncthreads();
    if (kt < 31) stage(cur ^ 1, kt + 1);
    f16x8 af[4], bf[4];
#pragma unroll
    for (int mi = 0; mi < 4; ++mi)
      af[mi] = *(const f16x8*)((const char*)&Ah[cur][0] + (wr * 64 + mi * 16 + lr) * 64 + lg * 16);
#pragma unroll
    for (int ni = 0; ni < 4; ++ni)
      bf[ni] = *(const f16x8*)((const char*)&Bh[cur][0] + (wc * 64 + ni * 16 + lr) * 64 + lg * 16);
#pragma unroll
    for (int mi = 0; mi < 4; ++mi)
#pragma unroll
      for (int ni = 0; ni < 4; ++ni)
        acc[mi][ni] = __builtin_amdgcn_mfma_f32_16x16x32_f16(af[mi], bf[ni], acc[mi][ni], 0, 0, 0);
    __syncthreads();
  }

#pragma unroll
  for (int mi = 0; mi < 4; ++mi) {
#pragma unroll
    for (int ni = 0; ni < 4; ++ni) {
      const int ncol = bn * 128 + wc * 64 + ni * 16 + lr;
#pragma unroll
      for (int j = 0; j < 4; ++j) {
        const int m = bm * 128 + wr * 64 + mi * 16 + lg * 4 + j;
        const float v = acc[mi][ni][j];
        if (MODE == 0) {
          const int nb = m >> 11, s = m & 2047;
          if (ncol < 1024) {
            const int hh = ncol >> 6, d = ncol & 63;
            Qb[(((size_t)(nb * 16 + hh)) * 2048 + s) * 64 + d] = (f16)v;
          } else if (ncol < 1536) {
            const int kh = (ncol - 1024) >> 6, d = ncol & 63;
            Kb[(((size_t)(nb * 8 + kh)) * 2048 + s) * 64 + d] = (f16)v;
          } else {
            const int vh = (ncol - 1536) >> 6, d = ncol & 63;
            VTb[(((size_t)(nb * 8 + vh)) * 64 + d) * 2048 + s] = (f16)v;
          }
        } else {
          Co[(size_t)m * 1024 + ncol] = v + bo[ncol];
        }
      }
    }
  }
}

// ---------------- flash attention, QBLK=64 (4 waves x 16 rows), KVBLK=64 ----------------
// Q head-major [n][h][2048][64] f16; K head-major [n][kvh][2048][64] f16;
// VT pre-transposed [n][kvh][64][2048] f16; Ob token-major [4096][1024] f16.
__global__ __launch_bounds__(256) void attn_k(
    const f16* __restrict__ Qb, const f16* __restrict__ Kb, const f16* __restrict__ VTb,
    f16* __restrict__ Ob)
{
  __shared__ __align__(16) f16 Kt[2][64][72];   // [kcol][d], 144B rows (padded)
  __shared__ __align__(16) f16 Vt[2][64][72];   // [d][k],    144B rows (padded)
  __shared__ __align__(16) f16 Pt[4][16][72];   // per-wave P [q][k]

  const int tid = threadIdx.x, w = tid >> 6, lane = tid & 63, lr = lane & 15, lg = lane >> 4;
  const int qt = blockIdx.x, nh = blockIdx.y;
  const int n = nh >> 4, h = nh & 15, kvh = h >> 1;
  const int qb = qt * 64;

  const f16* Qp = Qb + ((size_t)(n * 16 + h) * 2048 + qb + w * 16 + lr) * 64;
  const f16x8 q0 = *(const f16x8*)(Qp + lg * 8);
  const f16x8 q1 = *(const f16x8*)(Qp + 32 + lg * 8);

  const f16* Kp = Kb + (size_t)(n * 8 + kvh) * 2048 * 64;
  const f16* Vp = VTb + (size_t)(n * 8 + kvh) * 64 * 2048;

  const int sr = tid >> 3;         // 0..31
  const int sc8 = (tid & 7) * 8;   // 0..56

  float m_r[4], l_r[4];
  f32x4 oacc[4];
#pragma unroll
  for (int j = 0; j < 4; ++j) { m_r[j] = -1e30f; l_r[j] = 0.f; }
#pragma unroll
  for (int d = 0; d < 4; ++d) { f32x4 z = {0.f, 0.f, 0.f, 0.f}; oacc[d] = z; }

  const float C1 = 0.18033688011112042f;              // log2(e)/8
  const float slt = exp2f(-(float)(h + 1)) * C1;      // slope * log2e / 8
  const float qpos0 = (float)(qb + w * 16 + lg * 4);

  f16x8 ka0 = *(const f16x8*)(Kp + (size_t)sr * 64 + sc8);
  f16x8 ka1 = *(const f16x8*)(Kp + (size_t)(sr + 32) * 64 + sc8);
  f16x8 va0 = *(const f16x8*)(Vp + (size_t)sr * 2048 + sc8);
  f16x8 va1 = *(const f16x8*)(Vp + (size_t)(sr + 32) * 2048 + sc8);
  *(f16x8*)&Kt[0][sr][sc8] = ka0;
  *(f16x8*)&Kt[0][sr + 32][sc8] = ka1;
  *(f16x8*)&Vt[0][sr][sc8] = va0;
  *(f16x8*)&Vt[0][sr + 32][sc8] = va1;

  for (int t = 0; t < 32; ++t) {
    const int cur = t & 1;
    __syncthreads();
    if (t < 31) {   // prefetch next K/V tile into regs (hidden under compute)
      const int kb2 = (t + 1) * 64;
      ka0 = *(const f16x8*)(Kp + (size_t)(kb2 + sr) * 64 + sc8);
      ka1 = *(const f16x8*)(Kp + (size_t)(kb2 + sr + 32) * 64 + sc8);
      va0 = *(const f16x8*)(Vp + (size_t)sr * 2048 + kb2 + sc8);
      va1 = *(const f16x8*)(Vp + (size_t)(sr + 32) * 2048 + kb2 + sc8);
    }
    // ---- S = Q K^T ----
    f32x4 e[4];
#pragma unroll
    for (int tt = 0; tt < 4; ++tt) {
      f16x8 b0 = *(const f16x8*)((const char*)&Kt[cur][0][0] + (tt * 16 + lr) * 144 + lg * 16);
      f16x8 b1 = *(const f16x8*)((const char*)&Kt[cur][0][0] + (tt * 16 + lr) * 144 + 64 + lg * 16);
      f32x4 c = {};
      c = __builtin_amdgcn_mfma_f32_16x16x32_f16(q0, b0, c, 0, 0, 0);
      c = __builtin_amdgcn_mfma_f32_16x16x32_f16(q1, b1, c, 0, 0, 0);
      e[tt] = c;
    }
    // ---- scores + ALiBi (exp2 domain) ----
    const float kpos0 = (float)(t * 64 + lr);
    float p4[4][4], pm[4];
#pragma unroll
    for (int j = 0; j < 4; ++j) pm[j] = -1e30f;
#pragma unroll
    for (int tt = 0; tt < 4; ++tt)
#pragma unroll
      for (int j = 0; j < 4; ++j) {
        float dist = fabsf((qpos0 + (float)j) - (kpos0 + (float)(tt * 16)));
        float s = e[tt][j] * C1 - dist * slt;
        p4[tt][j] = s;
        pm[j] = fmaxf(pm[j], s);
      }
#pragma unroll
    for (int j = 0; j < 4; ++j) {
      pm[j] = fmaxf(pm[j], __shfl_xor(pm[j], 1));
      pm[j] = fmaxf(pm[j], __shfl_xor(pm[j], 2));
      pm[j] = fmaxf(pm[j], __shfl_xor(pm[j], 4));
      pm[j] = fmaxf(pm[j], __shfl_xor(pm[j], 8));
    }
    float al[4], ps[4];
#pragma unroll
    for (int j = 0; j < 4; ++j) {
      float mn = fmaxf(m_r[j], pm[j]);
      al[j] = exp2f(m_r[j] - mn);
      m_r[j] = mn;
      ps[j] = 0.f;
    }
#pragma unroll
    for (int tt = 0; tt < 4; ++tt)
#pragma unroll
      for (int j = 0; j < 4; ++j) {
        float p = exp2f(p4[tt][j] - m_r[j]);
        p4[tt][j] = p;
        ps[j] += p;
      }
#pragma unroll
    for (int j = 0; j < 4; ++j) {
      ps[j] += __shfl_xor(ps[j], 1);
      ps[j] += __shfl_xor(ps[j], 2);
      ps[j] += __shfl_xor(ps[j], 4);
      ps[j] += __shfl_xor(ps[j], 8);
      l_r[j] = l_r[j] * al[j] + ps[j];
    }
#pragma unroll
    for (int dt = 0; dt < 4; ++dt) {
      f32x4 o = oacc[dt];
      o[0] *= al[0]; o[1] *= al[1]; o[2] *= al[2]; o[3] *= al[3];
      oacc[dt] = o;
    }
    // ---- P -> per-wave LDS (layout fix for A-fragment) ----
#pragma unroll
    for (int tt = 0; tt < 4; ++tt)
#pragma unroll
      for (int j = 0; j < 4; ++j)
        Pt[w][lg * 4 + j][tt * 16 + lr] = (f16)p4[tt][j];
    // ---- O += P V ----
    f16x8 pa0 = *(const f16x8*)((const char*)&Pt[w][0][0] + lr * 144 + lg * 16);
    f16x8 pa1 = *(const f16x8*)((const char*)&Pt[w][0][0] + lr * 144 + 64 + lg * 16);
#pragma unroll
    for (int dt = 0; dt < 4; ++dt) {
      f16x8 vb0 = *(const f16x8*)((const char*)&Vt[cur][0][0] + (dt * 16 + lr) * 144 + lg * 16);
      f16x8 vb1 = *(const f16x8*)((const char*)&Vt[cur][0][0] + (dt * 16 + lr) * 144 + 64 + lg * 16);
      oacc[dt] = __builtin_amdgcn_mfma_f32_16x16x32_f16(pa0, vb0, oacc[dt], 0, 0, 0);
      oacc[dt] = __builtin_amdgcn_mfma_f32_16x16x32_f16(pa1, vb1, oacc[dt], 0, 0, 0);
    }
    __syncthreads();
    if (t < 31) {
      const int nb = cur ^ 1;
      *(f16x8*)&Kt[nb][sr][sc8] = ka0;
      *(f16x8*)&Kt[nb][sr + 32][sc8] = ka1;
      *(f16x8*)&Vt[nb][sr][sc8] = va0;
      *(f16x8*)&Vt[nb][sr + 32][sc8] = va1;
    }
  }
  // ---- normalize + store O (token-major f16) ----
  const int token = n * 2048 + qb + w * 16 + lg * 4;
  float inv[4];
#pragma unroll
  for (int j = 0; j < 4; ++j) inv[j] = 1.0f / l_r[j];
#pragma unroll
  for (int dt = 0; dt < 4; ++dt)
#pragma unroll
    for (int j = 0; j < 4; ++j)
      Ob[(size_t)(token + j) * 1024 + h * 64 + dt * 16 + lr] = (f16)(oacc[dt][j] * inv[j]);
}

extern "C" void kernel_launch(void* const* d_in, const int* in_sizes, int n_in,
                              void* d_out, int out_size, void* d_ws, size_t ws_size,
                              hipStream_t stream) {
  const float* x  = (const float*)d_in[0];
  const float* Wq = (const float*)d_in[1];
  const float* Wk = (const float*)d_in[2];
  const float* Wv = (const float*)d_in[3];
  const float* Wo = (const float*)d_in[4];
  const float* bo = (const float*)d_in[5];

  char* ws = (char*)d_ws;
  f16* xh  = (f16*)(ws);
  f16* wqh = (f16*)(ws + 8388608);
  f16* wkh = (f16*)(ws + 10485760);
  f16* wvh = (f16*)(ws + 11534336);
  f16* woh = (f16*)(ws + 12582912);
  f16* Qb  = (f16*)(ws + 14680064);
  f16* Kb  = (f16*)(ws + 23068672);
  f16* VTb = (f16*)(ws + 27262976);
  f16* Ob  = (f16*)(ws + 31457280);

  cvt_all<<<7168, 256, 0, stream>>>(x, Wq, Wk, Wv, Wo, xh, wqh, wkh, wvh, woh);
  gemm_k<0><<<512, 256, 0, stream>>>(xh, wqh, wkh, wvh, Qb, Kb, VTb, nullptr, nullptr);
  attn_k<<<dim3(32, 32), 256, 0, stream>>>(Qb, Kb, VTb, Ob);
  gemm_k<1><<<256, 256, 0, stream>>>(Ob, woh, nullptr, nullptr, nullptr, nullptr, nullptr, bo, (float*)d_out);
}

// Round 2
// 139.390 us; speedup vs baseline: 1.4998x; 1.4998x over previous
//
#include <hip/hip_runtime.h>

typedef _Float16 f16;
typedef f16 f16x8 __attribute__((ext_vector_type(8)));
typedef f16 f16x4 __attribute__((ext_vector_type(4)));
typedef float f32x4 __attribute__((ext_vector_type(4)));
typedef float f32x16 __attribute__((ext_vector_type(16)));
typedef unsigned uint4v __attribute__((ext_vector_type(4)));

#define GLL(g, l) __builtin_amdgcn_global_load_lds((const __attribute__((address_space(1))) void*)(g), (__attribute__((address_space(3))) void*)(l), 16, 0, 0)

// ---------------- fp32 -> fp16 convert (x, Wq, Wk, Wv, Wo) ----------------
__global__ __launch_bounds__(256) void cvt_all(
    const float* __restrict__ x, const float* __restrict__ wq, const float* __restrict__ wk,
    const float* __restrict__ wv, const float* __restrict__ wo,
    f16* __restrict__ xh, f16* __restrict__ wqh, f16* __restrict__ wkh,
    f16* __restrict__ wvh, f16* __restrict__ woh)
{
  int i = blockIdx.x * 256 + threadIdx.x;   // vec4 index, total 1835008
  const float4* src; f16x4* dst; int off;
  if (i < 1048576)      { src = (const float4*)x;  dst = (f16x4*)xh;  off = i; }
  else if (i < 1310720) { src = (const float4*)wq; dst = (f16x4*)wqh; off = i - 1048576; }
  else if (i < 1441792) { src = (const float4*)wk; dst = (f16x4*)wkh; off = i - 1310720; }
  else if (i < 1572864) { src = (const float4*)wv; dst = (f16x4*)wvh; off = i - 1441792; }
  else                  { src = (const float4*)wo; dst = (f16x4*)woh; off = i - 1572864; }
  float4 v = src[off];
  f16x4 hv; hv[0] = (f16)v.x; hv[1] = (f16)v.y; hv[2] = (f16)v.z; hv[3] = (f16)v.w;
  dst[off] = hv;
}

// ---------------- GEMM: C = A(MxK) * B(NxK)^T, K=1024, tile 128x128, BK=32 ----------------
// MODE 0: QKV projection. N = 2048 (Q 0..1023, K 1024..1535, V 1536..2047).
//         Writes Q head-major f16, K head-major f16, V TRANSPOSED ([n][kvh][64][2048]) f16.
// MODE 1: out projection. N = 1024. Writes f32 + bias to Co.
template<int MODE>
__global__ __launch_bounds__(256) void gemm_k(
    const f16* __restrict__ A, const f16* __restrict__ B0, const f16* __restrict__ B1,
    const f16* __restrict__ B2,
    f16* __restrict__ Qb, f16* __restrict__ Kb, f16* __restrict__ VTb,
    const float* __restrict__ bo, float* __restrict__ Co)
{
  __shared__ __align__(16) f16 Ah[2][4096];
  __shared__ __align__(16) f16 Bh[2][4096];
  const int tid = threadIdx.x;
  const int bm = blockIdx.x & 31, bn = blockIdx.x >> 5;
  const f16* Bp;
  if (MODE == 0) {
    if (bn < 8)       Bp = B0 + (size_t)bn * 131072;
    else if (bn < 12) Bp = B1 + (size_t)(bn - 8) * 131072;
    else              Bp = B2 + (size_t)(bn - 12) * 131072;
  } else {
    Bp = B0 + (size_t)bn * 131072;
  }
  const f16* Ap = A + (size_t)bm * 131072;

  const int w = tid >> 6, lane = tid & 63, lr = lane & 15, lg = lane >> 4;
  const int wr = w >> 1, wc = w & 1;

  auto stage = [&](int b, int kt) {
#pragma unroll
    for (int i = 0; i < 2; ++i) {
      int o = tid * 16 + i * 4096;          // byte offset within the 8KB tile
      int row = o >> 6, colb = o & 63;
      GLL((const char*)Ap + (size_t)row * 2048 + kt * 64 + colb, (char*)&Ah[b][0] + o);
      GLL((const char*)Bp + (size_t)row * 2048 + kt * 64 + colb, (char*)&Bh[b][0] + o);
    }
  };

  f32x4 acc[4][4] = {};

  stage(0, 0);
  for (int kt = 0; kt < 32; ++kt) {
    const int cur = kt & 1;
    __syncthreads();
    if (kt < 31) stage(cur ^ 1, kt + 1);
    f16x8 af[4], bf[4];
#pragma unroll
    for (int mi = 0; mi < 4; ++mi)
      af[mi] = *(const f16x8*)((const char*)&Ah[cur][0] + (wr * 64 + mi * 16 + lr) * 64 + lg * 16);
#pragma unroll
    for (int ni = 0; ni < 4; ++ni)
      bf[ni] = *(const f16x8*)((const char*)&Bh[cur][0] + (wc * 64 + ni * 16 + lr) * 64 + lg * 16);
#pragma unroll
    for (int mi = 0; mi < 4; ++mi)
#pragma unroll
      for (int ni = 0; ni < 4; ++ni)
        acc[mi][ni] = __builtin_amdgcn_mfma_f32_16x16x32_f16(af[mi], bf[ni], acc[mi][ni], 0, 0, 0);
    __syncthreads();
  }

#pragma unroll
  for (int mi = 0; mi < 4; ++mi) {
#pragma unroll
    for (int ni = 0; ni < 4; ++ni) {
      const int ncol = bn * 128 + wc * 64 + ni * 16 + lr;
#pragma unroll
      for (int j = 0; j < 4; ++j) {
        const int m = bm * 128 + wr * 64 + mi * 16 + lg * 4 + j;
        const float v = acc[mi][ni][j];
        if (MODE == 0) {
          const int nb = m >> 11, s = m & 2047;
          if (ncol < 1024) {
            const int hh = ncol >> 6, d = ncol & 63;
            Qb[(((size_t)(nb * 16 + hh)) * 2048 + s) * 64 + d] = (f16)v;
          } else if (ncol < 1536) {
            const int kh = (ncol - 1024) >> 6, d = ncol & 63;
            Kb[(((size_t)(nb * 8 + kh)) * 2048 + s) * 64 + d] = (f16)v;
          } else {
            const int vh = (ncol - 1536) >> 6, d = ncol & 63;
            VTb[(((size_t)(nb * 8 + vh)) * 64 + d) * 2048 + s] = (f16)v;
          }
        } else {
          Co[(size_t)m * 1024 + ncol] = v + bo[ncol];
        }
      }
    }
  }
}

// ---------------- flash attention, swapped-operand 32x32 structure ----------------
// 4 warps x 32 q-rows = 128 q/block. KVBLK=64, D=64.
// QK^T computed as mfma(K,Q) -> S^T: lane owns q=lane&31 column, scores in regs.
// Softmax fully in-register (+1 shfl_xor(32) partner combine). P -> B-frag via
// cvt_pkrtz + v_permlane32_swap_b32. PV as mfma(V^T,P^T) -> O^T: rescale/normalize
// are per-lane scalars. K/V staged via global_load_lds with pre-swizzled source.
__global__ __launch_bounds__(256, 2) void attn_k(
    const f16* __restrict__ Qb, const f16* __restrict__ Kb, const f16* __restrict__ VTb,
    f16* __restrict__ Ob)
{
  __shared__ __align__(16) f16 KV[2][2][4096];   // [buf][K|V][64 rows x 64 f16], XOR-swizzled

  const int tid = threadIdx.x, w = tid >> 6, l = tid & 63;
  const int lq = l & 31, hi = l >> 5;
  const int qt = blockIdx.x, nh = blockIdx.y;
  const int n = nh >> 4, h = nh & 15, kvh = h >> 1;
  const int qb = qt * 128;
  const int qhat = qb + w * 32 + lq;

  // Q fragments: lane needs Q[qhat][16*cd + 8*hi .. +7] for cd=0..3
  const f16* Qp = Qb + ((size_t)(n * 16 + h) * 2048 + qhat) * 64;
  f16x8 qf[4];
#pragma unroll
  for (int cd = 0; cd < 4; ++cd)
    qf[cd] = *(const f16x8*)(Qp + cd * 16 + hi * 8);

  const char* Kg = (const char*)(Kb + (size_t)(n * 8 + kvh) * 2048 * 64);   // [2048][64] f16, 128B rows
  const char* Vg = (const char*)(VTb + (size_t)(n * 8 + kvh) * 64 * 2048);  // [64][2048] f16, 4096B rows

  // staging: 256 threads x 16B x 2 shots = 8KB per buffer. LDS linear dest,
  // source chunk XOR-swizzled so that swizzled ds_reads are conflict-free.
  const int s0 = tid * 16, s1 = tid * 16 + 4096;
  const int r0 = s0 >> 7, c0 = ((s0 >> 4) & 7) ^ (r0 & 7);
  const int r1 = s1 >> 7, c1 = ((s1 >> 4) & 7) ^ (r1 & 7);

  auto stageK = [&](int buf, int tb) {
    GLL(Kg + (size_t)(tb * 64 + r0) * 128 + c0 * 16, (char*)&KV[buf][0][0] + s0);
    GLL(Kg + (size_t)(tb * 64 + r1) * 128 + c1 * 16, (char*)&KV[buf][0][0] + s1);
  };
  auto stageV = [&](int buf, int tb) {
    GLL(Vg + (size_t)r0 * 4096 + tb * 128 + c0 * 16, (char*)&KV[buf][1][0] + s0);
    GLL(Vg + (size_t)r1 * 4096 + tb * 128 + c1 * 16, (char*)&KV[buf][1][0] + s1);
  };

  f32x16 oacc[2] = {};
  float p[2][16];
  float m_r = -1e30f, l_r = 0.f;
  const float C1 = 0.18033688011112042f;           // log2(e)/8 (folds 1/sqrt(64))
  const float slt = exp2f(-(float)(h + 1)) * C1;   // alibi slope in exp2 domain
  const float qpos = (float)qhat;

  stageK(0, 0); stageV(0, 0);

  for (int t = 0; t < 32; ++t) {
    const int cur = t & 1;
    __syncthreads();                       // compiler drains vmcnt before s_barrier
    if (t < 31) { stageK(cur ^ 1, t + 1); stageV(cur ^ 1, t + 1); }

    // ---- S^T = K * Q^T : C[m=k_local][n=q], lane owns column q=lq ----
#pragma unroll
    for (int kt = 0; kt < 2; ++kt) {
      f32x16 c = {};
#pragma unroll
      for (int cd = 0; cd < 4; ++cd) {
        const int row = kt * 32 + lq;
        f16x8 kf = *(const f16x8*)((const char*)&KV[cur][0][0] + row * 128 + (((2 * cd + hi) ^ (row & 7)) * 16));
        c = __builtin_amdgcn_mfma_f32_32x32x16_f16(kf, qf[cd], c, 0, 0, 0);
      }
      const float kb0 = (float)(t * 64 + kt * 32 + 4 * hi);
#pragma unroll
      for (int r = 0; r < 16; ++r) {
        float kpos = kb0 + (float)((r & 3) + 8 * (r >> 2));
        p[kt][r] = c[r] * C1 - fabsf(qpos - kpos) * slt;
      }
    }
    // ---- in-register softmax (q is lane-local) ----
    float pmax = p[0][0];
#pragma unroll
    for (int kt = 0; kt < 2; ++kt)
#pragma unroll
      for (int r = 0; r < 16; ++r) pmax = fmaxf(pmax, p[kt][r]);
    pmax = fmaxf(pmax, __shfl_xor(pmax, 32));

    if (!__all(pmax - m_r <= 8.0f)) {      // defer-max: rescale only when needed
      float mn = fmaxf(m_r, pmax);
      float sc = __builtin_amdgcn_exp2f(m_r - mn);
      m_r = mn; l_r *= sc;
#pragma unroll
      for (int dt = 0; dt < 2; ++dt)
#pragma unroll
        for (int r = 0; r < 16; ++r) oacc[dt][r] *= sc;
    }
    float ps = 0.f;
#pragma unroll
    for (int kt = 0; kt < 2; ++kt)
#pragma unroll
      for (int r = 0; r < 16; ++r) {
        float e = __builtin_amdgcn_exp2f(p[kt][r] - m_r);
        p[kt][r] = e; ps += e;
      }
    ps += __shfl_xor(ps, 32);
    l_r += ps;

    // ---- P^T B-fragments: cvt_pkrtz pairs + permlane32_swap ----
    f16x8 pf[4];
#pragma unroll
    for (int c2 = 0; c2 < 4; ++c2) {
      const int T = c2 >> 1, e = c2 & 1;
      unsigned w0 = __builtin_bit_cast(unsigned, __builtin_amdgcn_cvt_pkrtz(p[T][8 * e + 0], p[T][8 * e + 1]));
      unsigned w2 = __builtin_bit_cast(unsigned, __builtin_amdgcn_cvt_pkrtz(p[T][8 * e + 4], p[T][8 * e + 5]));
      unsigned w1 = __builtin_bit_cast(unsigned, __builtin_amdgcn_cvt_pkrtz(p[T][8 * e + 2], p[T][8 * e + 3]));
      unsigned w3 = __builtin_bit_cast(unsigned, __builtin_amdgcn_cvt_pkrtz(p[T][8 * e + 6], p[T][8 * e + 7]));
      asm volatile("v_permlane32_swap_b32 %0, %1" : "+v"(w0), "+v"(w2));
      asm volatile("v_permlane32_swap_b32 %0, %1" : "+v"(w1), "+v"(w3));
      uint4v pu; pu.x = w0; pu.y = w1; pu.z = w2; pu.w = w3;
      pf[c2] = __builtin_bit_cast(f16x8, pu);
    }

    // ---- O^T += V^T * P^T : C[m=d][n=q] ----
#pragma unroll
    for (int dt = 0; dt < 2; ++dt) {
#pragma unroll
      for (int ck = 0; ck < 4; ++ck) {
        const int row = dt * 32 + lq;
        f16x8 vf = *(const f16x8*)((const char*)&KV[cur][1][0] + row * 128 + (((2 * ck + hi) ^ (row & 7)) * 16));
        oacc[dt] = __builtin_amdgcn_mfma_f32_32x32x16_f16(vf, pf[ck], oacc[dt], 0, 0, 0);
      }
    }
  }

  // ---- transpose O^T -> O via LDS (reuse K/V buffers), coalesced f16 store ----
  __syncthreads();
  f16* Ot = (f16*)&KV[0][0][0];            // [128 q][72 d]
  const float invl = 1.0f / l_r;
#pragma unroll
  for (int dt = 0; dt < 2; ++dt)
#pragma unroll
    for (int r = 0; r < 16; ++r) {
      const int d = dt * 32 + (r & 3) + 8 * (r >> 2) + 4 * hi;
      Ot[(w * 32 + lq) * 72 + d] = (f16)(oacc[dt][r] * invl);
    }
  __syncthreads();
  {
    const int q = tid >> 1, hf = tid & 1;
    const f16* src = &Ot[q * 72 + hf * 32];
    f16* dst = Ob + (size_t)(n * 2048 + qb + q) * 1024 + h * 64 + hf * 32;
#pragma unroll
    for (int i = 0; i < 4; ++i)
      *(f16x8*)(dst + i * 8) = *(const f16x8*)(src + i * 8);
  }
}

extern "C" void kernel_launch(void* const* d_in, const int* in_sizes, int n_in,
                              void* d_out, int out_size, void* d_ws, size_t ws_size,
                              hipStream_t stream) {
  const float* x  = (const float*)d_in[0];
  const float* Wq = (const float*)d_in[1];
  const float* Wk = (const float*)d_in[2];
  const float* Wv = (const float*)d_in[3];
  const float* Wo = (const float*)d_in[4];
  const float* bo = (const float*)d_in[5];

  char* ws = (char*)d_ws;
  f16* xh  = (f16*)(ws);
  f16* wqh = (f16*)(ws + 8388608);
  f16* wkh = (f16*)(ws + 10485760);
  f16* wvh = (f16*)(ws + 11534336);
  f16* woh = (f16*)(ws + 12582912);
  f16* Qb  = (f16*)(ws + 14680064);
  f16* Kb  = (f16*)(ws + 23068672);
  f16* VTb = (f16*)(ws + 27262976);
  f16* Ob  = (f16*)(ws + 31457280);

  cvt_all<<<7168, 256, 0, stream>>>(x, Wq, Wk, Wv, Wo, xh, wqh, wkh, wvh, woh);
  gemm_k<0><<<512, 256, 0, stream>>>(xh, wqh, wkh, wvh, Qb, Kb, VTb, nullptr, nullptr);
  attn_k<<<dim3(16, 32), 256, 0, stream>>>(Qb, Kb, VTb, Ob);
  gemm_k<1><<<256, 256, 0, stream>>>(Ob, woh, nullptr, nullptr, nullptr, nullptr, nullptr, bo, (float*)d_out);
}

// Round 3
// 133.410 us; speedup vs baseline: 1.5670x; 1.0448x over previous
//
#include <hip/hip_runtime.h>

typedef _Float16 f16;
typedef f16 f16x8 __attribute__((ext_vector_type(8)));
typedef f16 f16x4 __attribute__((ext_vector_type(4)));
typedef float f32x4 __attribute__((ext_vector_type(4)));
typedef float f32x16 __attribute__((ext_vector_type(16)));
typedef unsigned uint4v __attribute__((ext_vector_type(4)));

#define GLL(g, l) __builtin_amdgcn_global_load_lds((const __attribute__((address_space(1))) void*)(g), (__attribute__((address_space(3))) void*)(l), 16, 0, 0)

// ---------------- fp32 -> fp16 convert (x, Wq, Wk, Wv, Wo) ----------------
__global__ __launch_bounds__(256) void cvt_all(
    const float* __restrict__ x, const float* __restrict__ wq, const float* __restrict__ wk,
    const float* __restrict__ wv, const float* __restrict__ wo,
    f16* __restrict__ xh, f16* __restrict__ wqh, f16* __restrict__ wkh,
    f16* __restrict__ wvh, f16* __restrict__ woh)
{
  int i = blockIdx.x * 256 + threadIdx.x;   // vec4 index, total 1835008
  const float4* src; f16x4* dst; int off;
  if (i < 1048576)      { src = (const float4*)x;  dst = (f16x4*)xh;  off = i; }
  else if (i < 1310720) { src = (const float4*)wq; dst = (f16x4*)wqh; off = i - 1048576; }
  else if (i < 1441792) { src = (const float4*)wk; dst = (f16x4*)wkh; off = i - 1310720; }
  else if (i < 1572864) { src = (const float4*)wv; dst = (f16x4*)wvh; off = i - 1441792; }
  else                  { src = (const float4*)wo; dst = (f16x4*)woh; off = i - 1572864; }
  float4 v = src[off];
  f16x4 hv; hv[0] = (f16)v.x; hv[1] = (f16)v.y; hv[2] = (f16)v.z; hv[3] = (f16)v.w;
  dst[off] = hv;
}

// ---------------- GEMM: C = A(MxK) * B(NxK)^T, K=1024, tile 128x128, BK=32 ----------------
template<int MODE>
__global__ __launch_bounds__(256) void gemm_k(
    const f16* __restrict__ A, const f16* __restrict__ B0, const f16* __restrict__ B1,
    const f16* __restrict__ B2,
    f16* __restrict__ Qb, f16* __restrict__ Kb, f16* __restrict__ VTb,
    const float* __restrict__ bo, float* __restrict__ Co)
{
  __shared__ __align__(16) f16 Ah[2][4096];
  __shared__ __align__(16) f16 Bh[2][4096];
  const int tid = threadIdx.x;
  const int bm = blockIdx.x & 31, bn = blockIdx.x >> 5;
  const f16* Bp;
  if (MODE == 0) {
    if (bn < 8)       Bp = B0 + (size_t)bn * 131072;
    else if (bn < 12) Bp = B1 + (size_t)(bn - 8) * 131072;
    else              Bp = B2 + (size_t)(bn - 12) * 131072;
  } else {
    Bp = B0 + (size_t)bn * 131072;
  }
  const f16* Ap = A + (size_t)bm * 131072;

  const int w = tid >> 6, lane = tid & 63, lr = lane & 15, lg = lane >> 4;
  const int wr = w >> 1, wc = w & 1;

  auto stage = [&](int b, int kt) {
#pragma unroll
    for (int i = 0; i < 2; ++i) {
      int o = tid * 16 + i * 4096;          // byte offset within the 8KB tile
      int row = o >> 6, colb = o & 63;
      GLL((const char*)Ap + (size_t)row * 2048 + kt * 64 + colb, (char*)&Ah[b][0] + o);
      GLL((const char*)Bp + (size_t)row * 2048 + kt * 64 + colb, (char*)&Bh[b][0] + o);
    }
  };

  f32x4 acc[4][4] = {};

  stage(0, 0);
  for (int kt = 0; kt < 32; ++kt) {
    const int cur = kt & 1;
    __syncthreads();
    if (kt < 31) stage(cur ^ 1, kt + 1);
    f16x8 af[4], bf[4];
#pragma unroll
    for (int mi = 0; mi < 4; ++mi)
      af[mi] = *(const f16x8*)((const char*)&Ah[cur][0] + (wr * 64 + mi * 16 + lr) * 64 + lg * 16);
#pragma unroll
    for (int ni = 0; ni < 4; ++ni)
      bf[ni] = *(const f16x8*)((const char*)&Bh[cur][0] + (wc * 64 + ni * 16 + lr) * 64 + lg * 16);
#pragma unroll
    for (int mi = 0; mi < 4; ++mi)
#pragma unroll
      for (int ni = 0; ni < 4; ++ni)
        acc[mi][ni] = __builtin_amdgcn_mfma_f32_16x16x32_f16(af[mi], bf[ni], acc[mi][ni], 0, 0, 0);
    __syncthreads();
  }

#pragma unroll
  for (int mi = 0; mi < 4; ++mi) {
#pragma unroll
    for (int ni = 0; ni < 4; ++ni) {
      const int ncol = bn * 128 + wc * 64 + ni * 16 + lr;
#pragma unroll
      for (int j = 0; j < 4; ++j) {
        const int m = bm * 128 + wr * 64 + mi * 16 + lg * 4 + j;
        const float v = acc[mi][ni][j];
        if (MODE == 0) {
          const int nb = m >> 11, s = m & 2047;
          if (ncol < 1024) {
            const int hh = ncol >> 6, d = ncol & 63;
            Qb[(((size_t)(nb * 16 + hh)) * 2048 + s) * 64 + d] = (f16)v;
          } else if (ncol < 1536) {
            const int kh = (ncol - 1024) >> 6, d = ncol & 63;
            Kb[(((size_t)(nb * 8 + kh)) * 2048 + s) * 64 + d] = (f16)v;
          } else {
            const int vh = (ncol - 1536) >> 6, d = ncol & 63;
            VTb[(((size_t)(nb * 8 + vh)) * 64 + d) * 2048 + s] = (f16)v;
          }
        } else {
          Co[(size_t)m * 1024 + ncol] = v + bo[ncol];
        }
      }
    }
  }
}

// ---------------- flash attention, swapped-operand 32x32, KV-split x2 ----------------
// 8 waves: waves 0-3 (half 0) do KV tiles 0..15, waves 4-7 (half 1) do 16..31.
// Each half: 4 warps x 32 q = 128 q rows, own double-buffered K/V LDS (64KB tot).
// S^T = mfma(K,Q): lane owns q column; softmax in-register; P via cvt_pkrtz +
// permlane32_swap; O^T = mfma(V^T,P^T). Flash-combine of halves via LDS epilogue.
__global__ __launch_bounds__(512, 4) void attn_k(
    const f16* __restrict__ Qb, const f16* __restrict__ Kb, const f16* __restrict__ VTb,
    f16* __restrict__ Ob)
{
  __shared__ __align__(16) char SMEM[65536];

  const int tid = threadIdx.x, w = tid >> 6, l = tid & 63;
  const int lq = l & 31, hi = l >> 5;
  const int half = w >> 2, g = w & 3;
  const int qt = blockIdx.x, nh = blockIdx.y;
  const int n = nh >> 4, h = nh & 15, kvh = h >> 1;
  const int qb = qt * 128;
  const int qhat = qb + g * 32 + lq;

  // Q fragments: lane needs Q[qhat][16*cd + 8*hi .. +7]
  const f16* Qp = Qb + ((size_t)(n * 16 + h) * 2048 + qhat) * 64;
  f16x8 qf[4];
#pragma unroll
  for (int cd = 0; cd < 4; ++cd)
    qf[cd] = *(const f16x8*)(Qp + cd * 16 + hi * 8);

  const char* Kg = (const char*)(Kb + (size_t)(n * 8 + kvh) * 2048 * 64);   // [2048][64] f16
  const char* Vg = (const char*)(VTb + (size_t)(n * 8 + kvh) * 64 * 2048);  // [64][2048] f16

  // staging by each half's 256 threads: linear LDS dest + XOR-swizzled source
  const int t256 = tid & 255;
  const int s0 = t256 * 16, s1 = s0 + 4096;
  const int r0 = s0 >> 7, c0 = ((s0 >> 4) & 7) ^ (r0 & 7);
  const int r1 = s1 >> 7, c1 = ((s1 >> 4) & 7) ^ (r1 & 7);
  char* KB0 = SMEM + half * 32768;   // per half: buf0 K@0 V@8192, buf1 K@16384 V@24576

  auto stageK = [&](int buf, int tb) {
    char* d = KB0 + buf * 16384;
    GLL(Kg + (size_t)(tb * 64 + r0) * 128 + c0 * 16, d + s0);
    GLL(Kg + (size_t)(tb * 64 + r1) * 128 + c1 * 16, d + s1);
  };
  auto stageV = [&](int buf, int tb) {
    char* d = KB0 + buf * 16384 + 8192;
    GLL(Vg + (size_t)r0 * 4096 + tb * 128 + c0 * 16, d + s0);
    GLL(Vg + (size_t)r1 * 4096 + tb * 128 + c1 * 16, d + s1);
  };

  f32x16 oacc[2] = {};
  float p[2][16];
  float m_r = -1e30f, l_r = 0.f;
  const float C1 = 0.18033688011112042f;           // log2(e)/8 (folds 1/sqrt(64))
  const float slt = exp2f(-(float)(h + 1)) * C1;   // alibi slope in exp2 domain
  const float qpos = (float)qhat;

  stageK(0, half * 16); stageV(0, half * 16);

  for (int t = 0; t < 16; ++t) {
    const int cur = t & 1;
    const int tb = half * 16 + t;
    __syncthreads();                       // compiler drains vmcnt before s_barrier
    if (t < 15) { stageK(cur ^ 1, tb + 1); stageV(cur ^ 1, tb + 1); }
    const char* Kl = KB0 + cur * 16384;
    const char* Vl = Kl + 8192;

    // ---- S^T = K * Q^T : lane owns column q=lq ----
#pragma unroll
    for (int kt = 0; kt < 2; ++kt) {
      f32x16 c = {};
#pragma unroll
      for (int cd = 0; cd < 4; ++cd) {
        const int row = kt * 32 + lq;
        f16x8 kf = *(const f16x8*)(Kl + row * 128 + (((2 * cd + hi) ^ (row & 7)) * 16));
        c = __builtin_amdgcn_mfma_f32_32x32x16_f16(kf, qf[cd], c, 0, 0, 0);
      }
      const float kb0 = (float)(tb * 64 + kt * 32 + 4 * hi);
#pragma unroll
      for (int r = 0; r < 16; ++r) {
        float kpos = kb0 + (float)((r & 3) + 8 * (r >> 2));
        p[kt][r] = c[r] * C1 - fabsf(qpos - kpos) * slt;
      }
    }
    // ---- in-register softmax ----
    float pmax = p[0][0];
#pragma unroll
    for (int kt = 0; kt < 2; ++kt)
#pragma unroll
      for (int r = 0; r < 16; ++r) pmax = fmaxf(pmax, p[kt][r]);
    pmax = fmaxf(pmax, __shfl_xor(pmax, 32));

    if (!__all(pmax - m_r <= 8.0f)) {      // defer-max
      float mn = fmaxf(m_r, pmax);
      float sc = __builtin_amdgcn_exp2f(m_r - mn);
      m_r = mn; l_r *= sc;
#pragma unroll
      for (int dt = 0; dt < 2; ++dt)
#pragma unroll
        for (int r = 0; r < 16; ++r) oacc[dt][r] *= sc;
    }
    float ps = 0.f;
#pragma unroll
    for (int kt = 0; kt < 2; ++kt)
#pragma unroll
      for (int r = 0; r < 16; ++r) {
        float e = __builtin_amdgcn_exp2f(p[kt][r] - m_r);
        p[kt][r] = e; ps += e;
      }
    ps += __shfl_xor(ps, 32);
    l_r += ps;

    // ---- P^T B-fragments: cvt_pkrtz + permlane32_swap ----
    f16x8 pf[4];
#pragma unroll
    for (int c2 = 0; c2 < 4; ++c2) {
      const int T = c2 >> 1, e = c2 & 1;
      unsigned w0 = __builtin_bit_cast(unsigned, __builtin_amdgcn_cvt_pkrtz(p[T][8 * e + 0], p[T][8 * e + 1]));
      unsigned w2 = __builtin_bit_cast(unsigned, __builtin_amdgcn_cvt_pkrtz(p[T][8 * e + 4], p[T][8 * e + 5]));
      unsigned w1 = __builtin_bit_cast(unsigned, __builtin_amdgcn_cvt_pkrtz(p[T][8 * e + 2], p[T][8 * e + 3]));
      unsigned w3 = __builtin_bit_cast(unsigned, __builtin_amdgcn_cvt_pkrtz(p[T][8 * e + 6], p[T][8 * e + 7]));
      asm volatile("v_permlane32_swap_b32 %0, %1" : "+v"(w0), "+v"(w2));
      asm volatile("v_permlane32_swap_b32 %0, %1" : "+v"(w1), "+v"(w3));
      uint4v pu; pu.x = w0; pu.y = w1; pu.z = w2; pu.w = w3;
      pf[c2] = __builtin_bit_cast(f16x8, pu);
    }

    // ---- O^T += V^T * P^T ----
#pragma unroll
    for (int dt = 0; dt < 2; ++dt) {
#pragma unroll
      for (int ck = 0; ck < 4; ++ck) {
        const int row = dt * 32 + lq;
        f16x8 vf = *(const f16x8*)(Vl + row * 128 + (((2 * ck + hi) ^ (row & 7)) * 16));
        oacc[dt] = __builtin_amdgcn_mfma_f32_32x32x16_f16(vf, pf[ck], oacc[dt], 0, 0, 0);
      }
    }
  }

  // ---- flash-combine of halves + transpose + store ----
  float* Xo = (float*)SMEM;                 // [4 g][32 q][66] f32 partial O^T (as [q][d])
  float* Xm = (float*)(SMEM + 33792);       // [4 g][32 q]
  float* Xl = (float*)(SMEM + 34304);       // [4 g][32 q]
  f16* Ot = (f16*)SMEM;                     // later: [128 q][72] f16

  __syncthreads();
  if (half) {                               // half 1 publishes partials
#pragma unroll
    for (int dt = 0; dt < 2; ++dt)
#pragma unroll
      for (int r = 0; r < 16; ++r) {
        const int d = dt * 32 + (r & 3) + 8 * (r >> 2) + 4 * hi;
        Xo[(g * 32 + lq) * 66 + d] = oacc[dt][r];
      }
    if (!hi) { Xm[g * 32 + lq] = m_r; Xl[g * 32 + lq] = l_r; }
  }
  __syncthreads();
  float fin[2][16];
  if (!half) {                              // half 0 merges
    const float m1 = Xm[g * 32 + lq], l1 = Xl[g * 32 + lq];
    const float mm = fmaxf(m_r, m1);
    const float a0 = __builtin_amdgcn_exp2f(m_r - mm);
    const float a1 = __builtin_amdgcn_exp2f(m1 - mm);
    const float linv = 1.0f / (l_r * a0 + l1 * a1);
#pragma unroll
    for (int dt = 0; dt < 2; ++dt)
#pragma unroll
      for (int r = 0; r < 16; ++r) {
        const int d = dt * 32 + (r & 3) + 8 * (r >> 2) + 4 * hi;
        fin[dt][r] = (oacc[dt][r] * a0 + Xo[(g * 32 + lq) * 66 + d] * a1) * linv;
      }
  }
  __syncthreads();
  if (!half) {                              // write transposed f16 tile
#pragma unroll
    for (int dt = 0; dt < 2; ++dt)
#pragma unroll
      for (int r = 0; r < 16; ++r) {
        const int d = dt * 32 + (r & 3) + 8 * (r >> 2) + 4 * hi;
        Ot[(g * 32 + lq) * 72 + d] = (f16)fin[dt][r];
      }
  }
  __syncthreads();
  {                                         // coalesced store: all 512 threads
    const int q = tid >> 2, seg = tid & 3;
    const f16* src = &Ot[q * 72 + seg * 16];
    f16* dst = Ob + (size_t)(n * 2048 + qb + q) * 1024 + h * 64 + seg * 16;
    *(f16x8*)(dst) = *(const f16x8*)(src);
    *(f16x8*)(dst + 8) = *(const f16x8*)(src + 8);
  }
}

extern "C" void kernel_launch(void* const* d_in, const int* in_sizes, int n_in,
                              void* d_out, int out_size, void* d_ws, size_t ws_size,
                              hipStream_t stream) {
  const float* x  = (const float*)d_in[0];
  const float* Wq = (const float*)d_in[1];
  const float* Wk = (const float*)d_in[2];
  const float* Wv = (const float*)d_in[3];
  const float* Wo = (const float*)d_in[4];
  const float* bo = (const float*)d_in[5];

  char* ws = (char*)d_ws;
  f16* xh  = (f16*)(ws);
  f16* wqh = (f16*)(ws + 8388608);
  f16* wkh = (f16*)(ws + 10485760);
  f16* wvh = (f16*)(ws + 11534336);
  f16* woh = (f16*)(ws + 12582912);
  f16* Qb  = (f16*)(ws + 14680064);
  f16* Kb  = (f16*)(ws + 23068672);
  f16* VTb = (f16*)(ws + 27262976);
  f16* Ob  = (f16*)(ws + 31457280);

  cvt_all<<<7168, 256, 0, stream>>>(x, Wq, Wk, Wv, Wo, xh, wqh, wkh, wvh, woh);
  gemm_k<0><<<512, 256, 0, stream>>>(xh, wqh, wkh, wvh, Qb, Kb, VTb, nullptr, nullptr);
  attn_k<<<dim3(16, 32), 512, 0, stream>>>(Qb, Kb, VTb, Ob);
  gemm_k<1><<<256, 256, 0, stream>>>(Ob, woh, nullptr, nullptr, nullptr, nullptr, nullptr, bo, (float*)d_out);
}